// Round 12
// baseline (13.502 us; speedup 1.0000x reference)
//
#include <hip/hip_runtime.h>
#include <math.h>

// NN-MSE (one-directional Chamfer) via MFMA, 2 dispatches. R8 math/structure
// (12.2us best, absmax 0) with ONE change: 1024-thread blocks -> 16 waves/CU
// (4/SIMD, was 2/SIMD) for 2x latency hiding at identical per-CU throughput.
// R11 lesson: no unrolling (VGPR cap 128 for big blocks; spills are silent).
//
// Math (verified R8): d2(n,m) = |s_n|^2 + (|t_m|^2 - 2 s_n.t_m); cross term
// by v_mfma_f32_32x32x16_f16:
//   A lanes<32: [shx,shy,shz,slx,sly,slz,1,1] (fp16 hi/lo split of src); >=32: 0
//   B col lane: [-2tx,-2ty,-2tz,-2tx,-2ty,-2tz,TNh,TNl] fp16, TN=|t|^2 hi/lo
//   C/D: col=lane&31, row=(reg&3)+8*(reg>>2)+4*(lane>>5)  [m74/m101]
//
// k1: 256 blocks x 1024 thr (16 waves = 4 src-tiles x 4 target-quarters).
//     Per-wave: one A-frag, 16 ds_read_b128 B-tiles, 16 MFMAs, min3 into
//     f32x16; shfl_xor(1,2,4) col prereduce -> part[] (16 cols, stride 18)
//     -> combine + block sum -> ws.  Staging: threads 0-511 only (4 tgt ea).
// k2: sum 256 partials -> loss.

#define THREADS 1024
#define SRC_BLK 128
#define PART_STRIDE 18

typedef __attribute__((ext_vector_type(8))) _Float16 half8;
typedef __attribute__((ext_vector_type(16))) float f32x16;

__device__ __forceinline__ unsigned short f16b(float x) {
    _Float16 hv = (_Float16)x;
    return __builtin_bit_cast(unsigned short, hv);
}
__device__ __forceinline__ float f16tof(unsigned short u) {
    return (float)__builtin_bit_cast(_Float16, u);
}

__global__ __launch_bounds__(THREADS, 4)
void nn_mfma_kernel(const float* __restrict__ coord,
                    const float* __restrict__ coord_t,
                    const float* __restrict__ Rm,
                    const float* __restrict__ tv,
                    float* __restrict__ ws,
                    int S, int NSC) {
    __shared__ uint4 Bfrag[2048];                 // 32 KB: one 16B entry/target
    __shared__ float part[128 * PART_STRIDE];     // 9 KB, padded stride
    __shared__ float SN_lds[128];
    __shared__ float wsum[2];

    const int tid  = threadIdx.x;
    const int bid  = blockIdx.x;
    const int b    = bid / NSC;
    const int sc   = bid - b * NSC;
    const int w    = tid >> 6;
    const int lane = tid & 63;
    const int col  = lane & 31;
    const int kh   = lane >> 5;
    const int wsrc = w >> 2;      // src-tile 0..3
    const int h    = w & 3;       // target quarter 0..3

    // ---- stage B fragments: 4 consecutive targets/thread (thr 0-511) ----
    {
        const float* tb = coord_t + (size_t)b * S * 3;
        for (int base = tid * 4; base < S; base += THREADS * 4) {
            const float4* g4 = reinterpret_cast<const float4*>(tb + (size_t)base * 3);
            const float4 q0 = g4[0], q1 = g4[1], q2 = g4[2];
            const float px[4] = {q0.x, q0.w, q1.z, q2.y};
            const float py[4] = {q0.y, q1.x, q1.w, q2.z};
            const float pz[4] = {q0.z, q1.y, q2.x, q2.w};
            #pragma unroll
            for (int k = 0; k < 4; ++k) {
                const float tx = px[k], ty = py[k], tz = pz[k];
                const float TN = __builtin_fmaf(tz, tz, __builtin_fmaf(ty, ty, tx*tx));
                const unsigned uhx = f16b(-2.f*tx), uhy = f16b(-2.f*ty), uhz = f16b(-2.f*tz);
                const unsigned TNh = f16b(TN);
                const unsigned TNl = f16b(TN - f16tof((unsigned short)TNh));
                uint4 wv;
                wv.x = uhx | (uhy << 16);
                wv.y = uhz | (uhx << 16);
                wv.z = uhy | (uhz << 16);
                wv.w = TNh | (TNl << 16);
                Bfrag[base + k] = wv;
            }
        }
    }

    // ---- A fragment: transformed source, fp16 hi/lo split ----
    half8 afrag;
    #pragma unroll
    for (int i = 0; i < 8; ++i) afrag[i] = (_Float16)0.0f;
    {
        const float* Rb = Rm + (size_t)b * 9;
        const float r00=Rb[0], r01=Rb[1], r02=Rb[2];
        const float r10=Rb[3], r11=Rb[4], r12=Rb[5];
        const float r20=Rb[6], r21=Rb[7], r22=Rb[8];
        const float t0=tv[3*b], t1=tv[3*b+1], t2=tv[3*b+2];

        const float* sp = coord + ((size_t)b*S + (size_t)sc*SRC_BLK + wsrc*32 + col) * 3;
        const float x = sp[0], y = sp[1], z = sp[2];
        const float sx = __builtin_fmaf(r00,x,__builtin_fmaf(r01,y,__builtin_fmaf(r02,z,t0)));
        const float sy = __builtin_fmaf(r10,x,__builtin_fmaf(r11,y,__builtin_fmaf(r12,z,t1)));
        const float sz = __builtin_fmaf(r20,x,__builtin_fmaf(r21,y,__builtin_fmaf(r22,z,t2)));
        const float SN = __builtin_fmaf(sz, sz, __builtin_fmaf(sy, sy, sx*sx));
        if (h == 0 && kh == 0) SN_lds[wsrc*32 + col] = SN;
        if (kh == 0) {
            const _Float16 shx = (_Float16)sx, shy = (_Float16)sy, shz = (_Float16)sz;
            afrag[0] = shx; afrag[1] = shy; afrag[2] = shz;
            afrag[3] = (_Float16)(sx - (float)shx);
            afrag[4] = (_Float16)(sy - (float)shy);
            afrag[5] = (_Float16)(sz - (float)shz);
            afrag[6] = (_Float16)1.0f; afrag[7] = (_Float16)1.0f;
        }
    }

    __syncthreads();

    // ---- main loop: 16 target tiles per wave (its quarter), 2 per iter ----
    f32x16 zf, mn;
    #pragma unroll
    for (int r = 0; r < 16; ++r) { zf[r] = 0.0f; mn[r] = 1e30f; }

    const uint4* Bp = &Bfrag[h*(S >> 2) + col];
    const int nit = S >> 8;                       // 8 for S=2048
    for (int it = 0; it < nit; ++it) {
        const half8 b0 = *reinterpret_cast<const half8*>(Bp + it*64);
        const half8 b1 = *reinterpret_cast<const half8*>(Bp + it*64 + 32);
        const f32x16 aA = __builtin_amdgcn_mfma_f32_32x32x16_f16(afrag, b0, zf, 0, 0, 0);
        const f32x16 aB = __builtin_amdgcn_mfma_f32_32x32x16_f16(afrag, b1, zf, 0, 0, 0);
        #pragma unroll
        for (int r = 0; r < 16; ++r)
            mn[r] = fminf(fminf(mn[r], aA[r]), aB[r]);    // v_min3
    }

    // ---- col prereduce (groups of 8) + write to padded part[] ----
    #pragma unroll
    for (int r = 0; r < 16; ++r) {
        float v = mn[r];
        v = fminf(v, __shfl_xor(v, 1, 64));
        v = fminf(v, __shfl_xor(v, 2, 64));
        v = fminf(v, __shfl_xor(v, 4, 64));
        if ((col & 7) == 0) {
            const int row = (r & 3) + 8*(r >> 2) + 4*kh;
            part[(wsrc*32 + row)*PART_STRIDE + h*4 + (col >> 3)] = v;
        }
    }
    __syncthreads();

    // ---- combine 16 partials/source, add |s|^2, clamp, block sum ----
    float acc = 0.0f;
    if (tid < 128) {
        const float* pp = &part[tid * PART_STRIDE];
        float m = pp[0];
        #pragma unroll
        for (int j = 1; j < 16; ++j) m = fminf(m, pp[j]);
        acc = fmaxf(SN_lds[tid] + m, 0.0f);
        #pragma unroll
        for (int off = 32; off > 0; off >>= 1) acc += __shfl_down(acc, off, 64);
        if ((tid & 63) == 0) wsum[tid >> 6] = acc;
    }
    __syncthreads();
    if (tid == 0) ws[bid] = wsum[0] + wsum[1];
}

__global__ __launch_bounds__(256)
void final_kernel(const float* __restrict__ partial, int n,
                  float* __restrict__ out, float scale) {
    float v = (threadIdx.x < n) ? partial[threadIdx.x] : 0.0f;
    #pragma unroll
    for (int off = 32; off > 0; off >>= 1) v += __shfl_down(v, off, 64);
    __shared__ float sm[4];
    if ((threadIdx.x & 63) == 0) sm[threadIdx.x >> 6] = v;
    __syncthreads();
    if (threadIdx.x == 0) out[0] = (sm[0] + sm[1] + sm[2] + sm[3]) * scale;
}

extern "C" void kernel_launch(void* const* d_in, const int* in_sizes, int n_in,
                              void* d_out, int out_size, void* d_ws, size_t ws_size,
                              hipStream_t stream) {
    const float* coord   = (const float*)d_in[0];
    const float* coord_t = (const float*)d_in[1];
    const float* Rm      = (const float*)d_in[2];
    const float* tv      = (const float*)d_in[3];

    const int B = in_sizes[2] / 9;            // R is [B,3,3]
    const int S = in_sizes[0] / (3 * B);      // coord is [B*S,3]
    const int NSC = S / SRC_BLK;              // 16
    const int nblk = B * NSC;                 // 256

    float* ws  = (float*)d_ws;
    float* out = (float*)d_out;

    nn_mfma_kernel<<<nblk, THREADS, 0, stream>>>(
        coord, coord_t, Rm, tv, ws, S, NSC);

    final_kernel<<<1, 256, 0, stream>>>(
        ws, nblk, out, 1.0f / ((float)B * (float)S));
}